// Round 1
// 70.798 us; speedup vs baseline: 1.0359x; 1.0359x over previous
//
#include <hip/hip_runtime.h>
#include <float.h>

#define OUTP 7
#define NCH 256
#define FH 50
#define FW 50
#define LDS_P 65            // 64 data cols + 1 pad float -> stride 65 mod 32 = 1 (conflict-free)
#define CH_PER_BLOCK 16     // 4 waves * 4 channels per wave

// v6: channel-packed waves.
//   One wave handles 4 channels of one ROI. Lanes are packed along the ROI
//   width: w<=16 -> 4 channels side-by-side in one pass; w<=32 -> 2 channels,
//   2 passes; w>32 (~12% of ROIs) -> 1 channel, 4 passes. Path is per-ROI
//   uniform (scalar branch on SGPR w).
//   rowmax LDS is per-quad and only read by the wave that wrote it, so the
//   block-wide __syncthreads() is replaced by wave-local s_waitcnt lgkmcnt(0).
//   Clamped-unroll row loads kept from v5: bin height <= 4 for h<=21, <= 8
//   for h<=50; duplicate clamped rows are L1 hits, all loads independent.

template<int KMAX>
__device__ __forceinline__ void row_phase(const float* __restrict__ lb, int h,
                                          bool active, float (&rm)[OUTP])
{
    #pragma unroll
    for (int i = 0; i < OUTP; ++i) rm[i] = -FLT_MAX;
    if (active) {
        #pragma unroll
        for (int i = 0; i < OUTP; ++i) {
            const int ys  = i * h / OUTP;                        // scalar (h in SGPR)
            const int ye1 = ((i + 1) * h + OUTP - 1) / OUTP - 1; // >= ys
            float v[KMAX];
            #pragma unroll
            for (int k = 0; k < KMAX; ++k)
                v[k] = lb[min(ys + k, ye1) * FW];
            #pragma unroll
            for (int s = KMAX / 2; s > 0; s >>= 1)
                #pragma unroll
                for (int k = 0; k < s; ++k)
                    v[k] = fmaxf(v[k], v[k + s]);
            rm[i] = v[0];
        }
    }
}

template<int SUBW, int NSUB>
__device__ __forceinline__ void do_rep(const float* __restrict__ lb, bool active,
                                       int h, int w,
                                       float (*rowmax)[LDS_P],
                                       float* __restrict__ outp,   // + (n,c_first) offset
                                       int lane)
{
    float rm[OUTP];
    if (h <= 21) row_phase<4>(lb, h, active, rm);
    else         row_phase<8>(lb, h, active, rm);

    // ensure the previous rep's epilogue LDS reads completed before overwrite
    asm volatile("s_waitcnt lgkmcnt(0)" ::: "memory");
    #pragma unroll
    for (int i = 0; i < OUTP; ++i) rowmax[i][lane] = rm[i];
    // wave-local visibility: same wave wrote and reads this quad's LDS
    asm volatile("s_waitcnt lgkmcnt(0)" ::: "memory");
    __builtin_amdgcn_sched_barrier(0);

    if (lane < OUTP * OUTP) {
        const int i  = lane / OUTP;
        const int j  = lane - i * OUTP;
        const int xs = j * w / OUTP;
        const int xe = ((j + 1) * w + OUTP - 1) / OUTP;   // <= w always
        #pragma unroll
        for (int sub = 0; sub < NSUB; ++sub) {
            float m = -FLT_MAX;
            for (int x = xs; x < xe; ++x)
                m = fmaxf(m, rowmax[i][sub * SUBW + x]);
            outp[sub * (OUTP * OUTP) + lane] = m;
        }
    }
}

__global__ __launch_bounds__(256) void roi_pool_v6(
    const float* __restrict__ features,   // (B,256,50,50)
    const float* __restrict__ cat_rois,   // (N,5): im,x1,y1,x2,y2
    float* __restrict__ out)              // (N,256,7,7)
{
    __shared__ float rowmax[4][OUTP][LDS_P];   // 7280 B, per-quad private

    const int lane = threadIdx.x & 63;
    const int quad = threadIdx.x >> 6;
    const int n    = blockIdx.x >> 4;                          // 16 blocks per ROI
    const int c0   = ((blockIdx.x & 15) << 4) + (quad << 2);   // 4 channels per wave

    const float* r5 = cat_rois + n * 5;
    const int im = __builtin_amdgcn_readfirstlane((int)rintf(r5[0]));
    const int x1 = __builtin_amdgcn_readfirstlane((int)rintf(r5[1] * 0.0625f));
    const int y1 = __builtin_amdgcn_readfirstlane((int)rintf(r5[2] * 0.0625f));
    const int x2 = __builtin_amdgcn_readfirstlane((int)rintf(r5[3] * 0.0625f));
    const int y2 = __builtin_amdgcn_readfirstlane((int)rintf(r5[4] * 0.0625f));

    const int h = y2 - y1 + 1;   // region fully in-bounds (clamps are no-ops)
    const int w = x2 - x1 + 1;

    const float* base0 = features + ((size_t)(im * NCH + c0)) * (FH * FW)
                                  + y1 * FW + x1;
    float* outp = out + ((size_t)n * NCH + c0) * (OUTP * OUTP);
    float (*rmq)[LDS_P] = rowmax[quad];

    if (w <= 16) {
        // 4 channels packed: lanes = sub(2b) x col(4b), one pass
        const int sub = lane >> 4, col = lane & 15;
        do_rep<16, 4>(base0 + sub * (FH * FW) + col, col < w, h, w,
                      rmq, outp, lane);
    } else if (w <= 32) {
        // 2 channels packed, two passes
        const int sub = lane >> 5, col = lane & 31;
        const bool act = col < w;
        #pragma unroll
        for (int rep = 0; rep < 2; ++rep)
            do_rep<32, 2>(base0 + (2 * rep + sub) * (FH * FW) + col, act, h, w,
                          rmq, outp + 2 * rep * (OUTP * OUTP), lane);
    } else {
        // wide ROI: 1 channel per pass, four passes
        const bool act = lane < w;
        #pragma unroll
        for (int rep = 0; rep < 4; ++rep)
            do_rep<64, 1>(base0 + rep * (FH * FW) + lane, act, h, w,
                          rmq, outp + rep * (OUTP * OUTP), lane);
    }
}

extern "C" void kernel_launch(void* const* d_in, const int* in_sizes, int n_in,
                              void* d_out, int out_size, void* d_ws, size_t ws_size,
                              hipStream_t stream) {
    const float* features = (const float*)d_in[0];
    const float* cat_rois = (const float*)d_in[1];
    float* out = (float*)d_out;

    const int N = in_sizes[1] / 5;            // 128 ROIs
    dim3 grid(N * (NCH / CH_PER_BLOCK));      // 2048 blocks, 4 waves each
    roi_pool_v6<<<grid, 256, 0, stream>>>(features, cat_rois, out);
}